// Round 11
// baseline (1289.503 us; speedup 1.0000x reference)
//
#include <hip/hip_runtime.h>
#include <hip/hip_cooperative_groups.h>
#include <math.h>

namespace cg = cooperative_groups;

#define N_NODES 50000
#define N_EDGES 800000
#define N_GRAPHS 64
#define F_INN 128
#define F_HID 192
#define F_OUTT 128
#define N_CLS 10

typedef short short8 __attribute__((ext_vector_type(8)));
typedef float f32x4 __attribute__((ext_vector_type(4)));

static __device__ inline unsigned short f2bf(float f) {
    unsigned int u = __float_as_uint(f);
    unsigned int r = (u + 0x7FFFu + ((u >> 16) & 1u)) >> 16;  // RNE
    return (unsigned short)r;
}
static __device__ inline float bf2f(unsigned short h) {
    return __uint_as_float(((unsigned int)h) << 16);
}

// ---------------- CSR build (regular launches: TLP-hungry) ----------------
__global__ void k_deg(const int* __restrict__ row, int* __restrict__ cnt,
                      int* __restrict__ rank) {
    int e = blockIdx.x * 256 + threadIdx.x;
    if (e < N_EDGES) rank[e] = atomicAdd(&cnt[row[e]], 1);
}

__global__ void k_scan1(const int* __restrict__ cnt, int* __restrict__ rp,
                        int* __restrict__ part, float* __restrict__ dis) {
    __shared__ int s[256];
    int base = blockIdx.x * 512;
    int i0 = base + 2 * threadIdx.x;
    int v0 = (i0 < N_NODES) ? cnt[i0] : 0;
    int v1 = (i0 + 1 < N_NODES) ? cnt[i0 + 1] : 0;
    if (i0 < N_NODES) dis[i0] = v0 > 0 ? rsqrtf((float)v0) : 0.f;
    if (i0 + 1 < N_NODES) dis[i0 + 1] = v1 > 0 ? rsqrtf((float)v1) : 0.f;
    int tsum = v0 + v1;
    s[threadIdx.x] = tsum;
    __syncthreads();
    for (int off = 1; off < 256; off <<= 1) {
        int val = (threadIdx.x >= off) ? s[threadIdx.x - off] : 0;
        __syncthreads();
        s[threadIdx.x] += val;
        __syncthreads();
    }
    int excl = s[threadIdx.x] - tsum;
    if (i0 < N_NODES) rp[i0] = excl;
    if (i0 + 1 < N_NODES) rp[i0 + 1] = excl + v0;
    if (threadIdx.x == 255) part[blockIdx.x] = s[255];
}

// scan phases 2+3 fused: each block reduces part[0..b-1] itself (nb<=128).
__global__ void k_scan3(int* __restrict__ rp, const int* __restrict__ part,
                        int nb) {
    __shared__ int s[128];
    int t = threadIdx.x;
    int b = blockIdx.x;
    if (t < 128) s[t] = (t < b && t < nb) ? part[t] : 0;
    __syncthreads();
    for (int off = 64; off > 0; off >>= 1) {
        if (t < off) s[t] += s[t + off];
        __syncthreads();
    }
    int add = s[0];
    int i0 = b * 512 + 2 * t;
    if (i0 < N_NODES) rp[i0] += add;
    if (i0 + 1 < N_NODES) rp[i0 + 1] += add;
    if (b == 0 && t == 0) rp[N_NODES] = N_EDGES;
}

__global__ void k_scatter(const int* __restrict__ row, const int* __restrict__ col,
                          const float* __restrict__ dis, const int* __restrict__ rp,
                          const int* __restrict__ rank, int2* __restrict__ cw) {
    int e = blockIdx.x * 256 + threadIdx.x;
    if (e < N_EDGES) {
        int r = row[e], c = col[e];
        int pos = rp[r] + rank[e];
        int2 v;
        v.x = c;
        v.y = __float_as_int(-dis[r] * dis[c]);
        cw[pos] = v;
    }
}

// ---------------- fused fp32->bf16 conversions + workspace zeroing ---------
// Chebyshev weight folding: out = Tx0(W0-W2) + G1*W1 + G2*(2*W2).
#define NX (N_NODES * F_INN)
#define NW1 (3 * 128 * 192)
#define NW2 (3 * 192 * 192)
#define NW3 (3 * 192 * 128)
#define NPS (N_GRAPHS * F_OUTT)
__global__ void k_convAll(const float* __restrict__ x, const float* __restrict__ W1,
                          const float* __restrict__ W2, const float* __restrict__ W3,
                          unsigned short* __restrict__ xb,
                          unsigned short* __restrict__ Wt1,
                          unsigned short* __restrict__ Wt2,
                          unsigned short* __restrict__ Wt3,
                          int* __restrict__ cnt, float* __restrict__ psum) {
    int idx = blockIdx.x * 256 + threadIdx.x;
    if (idx < NX) {
        xb[idx] = f2bf(x[idx]);
        return;
    }
    idx -= NX;
    if (idx < NW1) {
        int per = 128 * 192;
        int j = idx / per, r = idx - j * per;
        int k = r / 192, n = r - k * 192;
        float v = (j == 0) ? (W1[idx] - W1[idx + 2 * per])
                           : (j == 2 ? 2.f * W1[idx] : W1[idx]);
        Wt1[j * per + n * 128 + k] = f2bf(v);
        return;
    }
    idx -= NW1;
    if (idx < NW2) {
        int per = 192 * 192;
        int j = idx / per, r = idx - j * per;
        int k = r / 192, n = r - k * 192;
        float v = (j == 0) ? (W2[idx] - W2[idx + 2 * per])
                           : (j == 2 ? 2.f * W2[idx] : W2[idx]);
        Wt2[j * per + n * 192 + k] = f2bf(v);
        return;
    }
    idx -= NW2;
    if (idx < NW3) {
        int per = 192 * 128;
        int j = idx / per, r = idx - j * per;
        int k = r / 128, n = r - k * 128;
        float v = (j == 0) ? (W3[idx] - W3[idx + 2 * per])
                           : (j == 2 ? 2.f * W3[idx] : W3[idx]);
        Wt3[j * per + n * 192 + k] = f2bf(v);
        return;
    }
    idx -= NW3;
    if (idx < N_NODES) {
        cnt[idx] = 0;
        return;
    }
    idx -= N_NODES;
    if (idx < NPS) psum[idx] = 0.f;
}

// ---------------- SpMV phase body: y = L_hat @ h (bf16, fp32 accum) -------
// Grid-stride over row-quads; one wave per row; readfirstlane-scalarized
// edge metadata; unroll x8. Structural floor: FETCH = h x ~7 XCD-replication
// at the ~3.7 TB/s fabric ceiling (round 8).
template <int F>
__device__ __forceinline__ void spmv_body(const int* __restrict__ rp,
                                          const int2* __restrict__ cw,
                                          const unsigned short* __restrict__ h,
                                          unsigned short* __restrict__ y) {
    constexpr bool EX = (F > 128);
    constexpr int FU = F / 2;
    int wave = threadIdx.x >> 6;
    int lane = threadIdx.x & 63;
    const unsigned int* hu = (const unsigned int*)h;
    for (int base = blockIdx.x * 4; base < N_NODES; base += gridDim.x * 4) {
        int r = base + wave;
        if (r >= N_NODES) continue;
        int e0 = __builtin_amdgcn_readfirstlane(rp[r]);
        int e1 = __builtin_amdgcn_readfirstlane(rp[r + 1]);
        float a0 = 0.f, a1 = 0.f, a2 = 0.f;
        int e = e0;
        for (; e + 8 <= e1; e += 8) {
            int colv[8];
            float wv[8];
#pragma unroll
            for (int u = 0; u < 8; u++) {
                int2 p = cw[e + u];
                colv[u] = __builtin_amdgcn_readfirstlane(p.x);
                wv[u] = __uint_as_float(__builtin_amdgcn_readfirstlane(p.y));
            }
            unsigned int g[8];
            unsigned short s[8];
#pragma unroll
            for (int u = 0; u < 8; u++) {
                g[u] = hu[colv[u] * FU + lane];
                if constexpr (EX) s[u] = h[colv[u] * F + 128 + lane];
            }
#pragma unroll
            for (int u = 0; u < 8; u++) {
                a0 += wv[u] * bf2f((unsigned short)g[u]);
                a1 += wv[u] * bf2f((unsigned short)(g[u] >> 16));
                if constexpr (EX) a2 += wv[u] * bf2f(s[u]);
            }
        }
        for (; e + 4 <= e1; e += 4) {
            int colv[4];
            float wv[4];
#pragma unroll
            for (int u = 0; u < 4; u++) {
                int2 p = cw[e + u];
                colv[u] = __builtin_amdgcn_readfirstlane(p.x);
                wv[u] = __uint_as_float(__builtin_amdgcn_readfirstlane(p.y));
            }
            unsigned int g[4];
            unsigned short s[4];
#pragma unroll
            for (int u = 0; u < 4; u++) {
                g[u] = hu[colv[u] * FU + lane];
                if constexpr (EX) s[u] = h[colv[u] * F + 128 + lane];
            }
#pragma unroll
            for (int u = 0; u < 4; u++) {
                a0 += wv[u] * bf2f((unsigned short)g[u]);
                a1 += wv[u] * bf2f((unsigned short)(g[u] >> 16));
                if constexpr (EX) a2 += wv[u] * bf2f(s[u]);
            }
        }
        for (; e < e1; e++) {
            int2 p = cw[e];
            int c = __builtin_amdgcn_readfirstlane(p.x);
            float w = __uint_as_float(__builtin_amdgcn_readfirstlane(p.y));
            unsigned int g = hu[c * FU + lane];
            a0 += w * bf2f((unsigned short)g);
            a1 += w * bf2f((unsigned short)(g >> 16));
            if constexpr (EX) a2 += w * bf2f(h[c * F + 128 + lane]);
        }
        ((unsigned int*)y)[r * FU + lane] =
            (unsigned int)f2bf(a0) | ((unsigned int)f2bf(a1) << 16);
        if constexpr (EX) y[r * F + 128 + lane] = f2bf(a2);
    }
}

// ---------------- GEMM phase body (bf16 MFMA, full-Fout per block) --------
// Grid-stride over M-tiles of 128. FUSE_POOL: pool fp32 tile into psum.
template <int Fin, int Fout, bool FUSE_POOL>
__device__ __forceinline__ void gemm_body(
    const unsigned short* __restrict__ A0, const unsigned short* __restrict__ A1,
    const unsigned short* __restrict__ A2, const unsigned short* __restrict__ Wt,
    const float* __restrict__ bias, unsigned short* __restrict__ C,
    const int* __restrict__ batch, float* __restrict__ psum,
    unsigned short* __restrict__ As, unsigned short* __restrict__ Bs) {
    constexpr int NF = Fout / 16;
    constexpr int BP = Fout / 64;
    constexpr int per = Fin * Fout;
    constexpr int nChunks = (3 * Fin) >> 5;
    int t = threadIdx.x;
    int w = t >> 6;
    int lane = t & 63;
    int ml = lane & 15;
    int quad = lane >> 4;
    int srow = t >> 2;
    int schunk = t & 3;

    for (int tb = blockIdx.x; tb * 128 < N_NODES; tb += gridDim.x) {
        int mBase = tb * 128;
        f32x4 acc[2][NF];
#pragma unroll
        for (int i = 0; i < 2; i++)
#pragma unroll
            for (int jn = 0; jn < NF; jn++) acc[i][jn] = (f32x4){0.f, 0.f, 0.f, 0.f};

        for (int ch = 0; ch < nChunks; ch++) {
            int kg = ch << 5;
            int j = kg / Fin;
            int kk = kg - j * Fin;
            const unsigned short* Aj = (j == 0) ? A0 : (j == 1) ? A1 : A2;
            if (ch > 0) __syncthreads();
#pragma unroll
            for (int pass = 0; pass < 2; pass++) {
                int row = srow + pass * 64;
                int gm = mBase + row;
                uint4 v = {0u, 0u, 0u, 0u};
                if (gm < N_NODES)
                    v = *(const uint4*)(Aj + (size_t)gm * Fin + kk + schunk * 8);
                *(uint4*)&As[row * 40 + schunk * 8] = v;
            }
#pragma unroll
            for (int pass = 0; pass < BP; pass++) {
                int row = srow + pass * 64;
                const unsigned short* src =
                    Wt + (size_t)j * per + (size_t)row * Fin + kk + schunk * 8;
                *(uint4*)&Bs[row * 40 + schunk * 8] = *(const uint4*)src;
            }
            __syncthreads();

            short8 afr[2];
#pragma unroll
            for (int i = 0; i < 2; i++)
                afr[i] = *(const short8*)&As[(w * 32 + i * 16 + ml) * 40 + quad * 8];
#pragma unroll
            for (int jn = 0; jn < NF; jn++) {
                short8 bfr = *(const short8*)&Bs[(jn * 16 + ml) * 40 + quad * 8];
#pragma unroll
                for (int i = 0; i < 2; i++)
                    acc[i][jn] = __builtin_amdgcn_mfma_f32_16x16x32_bf16(
                        afr[i], bfr, acc[i][jn], 0, 0, 0);
            }
        }

        float biasv[NF];
#pragma unroll
        for (int jn = 0; jn < NF; jn++) biasv[jn] = bias[jn * 16 + ml];

        if constexpr (!FUSE_POOL) {
#pragma unroll
            for (int i = 0; i < 2; i++) {
#pragma unroll
                for (int r = 0; r < 4; r++) {
                    int m = mBase + w * 32 + i * 16 + quad * 4 + r;
                    if (m < N_NODES) {
                        unsigned short* cp = C + (size_t)m * Fout + ml;
#pragma unroll
                        for (int jn = 0; jn < NF; jn++)
                            cp[jn * 16] = f2bf(acc[i][jn][r] + biasv[jn]);
                    }
                }
            }
        } else {
            int m0 = mBase + w * 32;
            if (m0 < N_NODES) {
                int mlast = m0 + 31;
                if (mlast >= N_NODES) mlast = N_NODES - 1;
                int g0 = batch[m0];
                int g1 = batch[mlast];
                if (g0 == g1) {
#pragma unroll
                    for (int jn = 0; jn < NF; jn++) {
                        float pv = 0.f;
#pragma unroll
                        for (int i = 0; i < 2; i++)
#pragma unroll
                            for (int r = 0; r < 4; r++) {
                                int m = m0 + i * 16 + quad * 4 + r;
                                if (m < N_NODES) pv += acc[i][jn][r] + biasv[jn];
                            }
                        pv += __shfl_xor(pv, 16);
                        pv += __shfl_xor(pv, 32);
                        if (lane < 16)
                            atomicAdd(&psum[g0 * F_OUTT + ml + jn * 16], pv);
                    }
                } else {
#pragma unroll
                    for (int i = 0; i < 2; i++)
#pragma unroll
                        for (int r = 0; r < 4; r++) {
                            int m = m0 + i * 16 + quad * 4 + r;
                            if (m < N_NODES) {
                                int g = batch[m];
#pragma unroll
                                for (int jn = 0; jn < NF; jn++)
                                    atomicAdd(&psum[g * F_OUTT + ml + jn * 16],
                                              acc[i][jn][r] + biasv[jn]);
                            }
                        }
                }
            }
        }
        __syncthreads();  // LDS safe before next tile's staging
    }
}

// ---------------- head: mean + fc + log_softmax ----------------
__device__ __forceinline__ void head_body(const float* __restrict__ psum,
                                          const int* __restrict__ batch,
                                          const float* __restrict__ fcw,
                                          const float* __restrict__ fcb,
                                          float* __restrict__ out) {
    int g = blockIdx.x;
    if (g >= N_GRAPHS) return;
    __shared__ float sl[N_CLS];
    int c = threadIdx.x;
    int a = 0, b = N_NODES;
    while (a < b) { int m = (a + b) >> 1; if (batch[m] < g) a = m + 1; else b = m; }
    int lo = a;
    a = lo; b = N_NODES;
    while (a < b) { int m = (a + b) >> 1; if (batch[m] < g + 1) a = m + 1; else b = m; }
    float inv = 1.f / fmaxf((float)(a - lo), 1.f);
    float l = 0.f;
    if (c < N_CLS) {
        l = fcb[c];
        for (int k = 0; k < F_OUTT; k++)
            l += psum[g * F_OUTT + k] * inv * fcw[k * N_CLS + c];
        sl[c] = l;
    }
    __syncthreads();
    if (c < N_CLS) {
        float m = -1e30f;
        for (int i = 0; i < N_CLS; i++) m = fmaxf(m, sl[i]);
        float s = 0.f;
        for (int i = 0; i < N_CLS; i++) s += expf(sl[i] - m);
        out[g * N_CLS + c] = l - m - logf(s);
    }
}

// ---------------- cooperative mega-kernel: 6 SpMV + 3 GEMM + head ---------
// 9 grid.sync()s replace 9 kernel-launch boundaries (~6us each). LDS is one
// shared 25.6KB arena (As 128x40 + Bs 192x40 shorts).
__global__ __launch_bounds__(256, 2) void k_mega(
    const int* rp, const int2* cw, const unsigned short* xb, unsigned short* bufA,
    unsigned short* bufB, unsigned short* bufC, unsigned short* bufD,
    const unsigned short* Wt1, const unsigned short* Wt2, const unsigned short* Wt3,
    const float* b1, const float* b2, const float* b3, const int* batch,
    float* psum, const float* fcw, const float* fcb, float* out) {
    __shared__ unsigned short smem[128 * 40 + 192 * 40];
    unsigned short* As = smem;
    unsigned short* Bs = smem + 128 * 40;
    cg::grid_group grid = cg::this_grid();

    spmv_body<128>(rp, cw, xb, bufB);
    grid.sync();
    spmv_body<128>(rp, cw, bufB, bufC);
    grid.sync();
    gemm_body<128, 192, false>(xb, bufB, bufC, Wt1, b1, bufA, batch, psum, As, Bs);
    grid.sync();
    spmv_body<192>(rp, cw, bufA, bufB);
    grid.sync();
    spmv_body<192>(rp, cw, bufB, bufC);
    grid.sync();
    gemm_body<192, 192, false>(bufA, bufB, bufC, Wt2, b2, bufD, batch, psum, As, Bs);
    grid.sync();
    spmv_body<192>(rp, cw, bufD, bufB);
    grid.sync();
    spmv_body<192>(rp, cw, bufB, bufC);
    grid.sync();
    gemm_body<192, 128, true>(bufD, bufB, bufC, Wt3, b3, nullptr, batch, psum, As,
                              Bs);
    grid.sync();
    head_body(psum, batch, fcw, fcb, out);
}

// ---------------- fallback standalone kernels (same bodies) ----------------
template <int F>
__global__ void k_spmv(const int* __restrict__ rp, const int2* __restrict__ cw,
                       const unsigned short* __restrict__ h,
                       unsigned short* __restrict__ y) {
    spmv_body<F>(rp, cw, h, y);
}

template <int Fin, int Fout, bool FUSE_POOL>
__global__ __launch_bounds__(256) void k_gemm3(
    const unsigned short* __restrict__ A0, const unsigned short* __restrict__ A1,
    const unsigned short* __restrict__ A2, const unsigned short* __restrict__ Wt,
    const float* __restrict__ bias, unsigned short* __restrict__ C,
    const int* __restrict__ batch, float* __restrict__ psum) {
    __shared__ unsigned short smem[128 * 40 + 192 * 40];
    gemm_body<Fin, Fout, FUSE_POOL>(A0, A1, A2, Wt, bias, C, batch, psum, smem,
                                    smem + 128 * 40);
}

__global__ void k_head(const float* __restrict__ psum, const int* __restrict__ batch,
                       const float* __restrict__ fcw, const float* __restrict__ fcb,
                       float* __restrict__ out) {
    head_body(psum, batch, fcw, fcb, out);
}

extern "C" void kernel_launch(void* const* d_in, const int* in_sizes, int n_in,
                              void* d_out, int out_size, void* d_ws, size_t ws_size,
                              hipStream_t stream) {
    const float* x = (const float*)d_in[0];
    const int* ei = (const int*)d_in[1];
    const int* batch = (const int*)d_in[2];
    const float* W1 = (const float*)d_in[3];
    const float* b1 = (const float*)d_in[4];
    const float* W2 = (const float*)d_in[5];
    const float* b2 = (const float*)d_in[6];
    const float* W3 = (const float*)d_in[7];
    const float* b3 = (const float*)d_in[8];
    const float* fcw = (const float*)d_in[9];
    const float* fcb = (const float*)d_in[10];
    float* out = (float*)d_out;
    const int* row = ei;
    const int* col = ei + N_EDGES;

    char* p = (char*)d_ws;
    auto carve = [&](size_t bytes) {
        char* q = p;
        p += (bytes + 255) & ~(size_t)255;
        return q;
    };
    int* cnt = (int*)carve(N_NODES * 4);
    int* rank = (int*)carve((size_t)N_EDGES * 4);
    float* dis = (float*)carve(N_NODES * 4);
    int* rp = (int*)carve((N_NODES + 1) * 4);
    int* part = (int*)carve(128 * 4);
    int2* cw = (int2*)carve((size_t)N_EDGES * 8);
    unsigned short* xb = (unsigned short*)carve((size_t)N_NODES * F_INN * 2);
    size_t hbytes = (size_t)N_NODES * 192 * 2;
    unsigned short* bufA = (unsigned short*)carve(hbytes);
    unsigned short* bufB = (unsigned short*)carve(hbytes);
    unsigned short* bufC = (unsigned short*)carve(hbytes);
    unsigned short* bufD = (unsigned short*)carve(hbytes);
    unsigned short* Wt1 = (unsigned short*)carve(NW1 * 2);
    unsigned short* Wt2 = (unsigned short*)carve(NW2 * 2);
    unsigned short* Wt3 = (unsigned short*)carve(NW3 * 2);
    float* psum = (float*)carve(NPS * 4);

    // front: conv+zero, CSR build (regular launches — TLP-hungry atomics)
    {
        int tot = NX + NW1 + NW2 + NW3 + N_NODES + NPS;
        k_convAll<<<(tot + 255) / 256, 256, 0, stream>>>(x, W1, W2, W3, xb, Wt1, Wt2,
                                                         Wt3, cnt, psum);
    }
    k_deg<<<(N_EDGES + 255) / 256, 256, 0, stream>>>(row, cnt, rank);
    int nb = (N_NODES + 511) / 512;  // 98
    k_scan1<<<nb, 256, 0, stream>>>(cnt, rp, part, dis);
    k_scan3<<<nb, 256, 0, stream>>>(rp, part, nb);
    k_scatter<<<(N_EDGES + 255) / 256, 256, 0, stream>>>(row, col, dis, rp, rank, cw);

    // tail: one cooperative kernel (6 spmv + 3 gemm + head, 9 grid syncs)
    int dev = 0;
    hipGetDevice(&dev);
    int coopOK = 0;
    hipDeviceGetAttribute(&coopOK, hipDeviceAttributeCooperativeLaunch, dev);
    int numCU = 0;
    hipDeviceGetAttribute(&numCU, hipDeviceAttributeMultiprocessorCount, dev);
    int maxB = 0;
    hipOccupancyMaxActiveBlocksPerMultiprocessor(&maxB, k_mega, 256, 0);

    if (coopOK && maxB > 0 && numCU > 0) {
        int grid = maxB * numCU;
        if (grid < 64) grid = 64;  // head needs 64 blocks (co-residency holds)
        const int* rpc = rp;
        const int2* cwc = cw;
        const unsigned short* xbc = xb;
        const unsigned short* w1c = Wt1;
        const unsigned short* w2c = Wt2;
        const unsigned short* w3c = Wt3;
        void* args[] = {(void*)&rpc, (void*)&cwc, (void*)&xbc,  (void*)&bufA,
                        (void*)&bufB, (void*)&bufC, (void*)&bufD, (void*)&w1c,
                        (void*)&w2c,  (void*)&w3c,  (void*)&b1,   (void*)&b2,
                        (void*)&b3,   (void*)&batch, (void*)&psum, (void*)&fcw,
                        (void*)&fcb,  (void*)&out};
        hipLaunchCooperativeKernel((void*)k_mega, dim3(grid), dim3(256), args, 0,
                                   stream);
    } else {
        const int spmvGrid = (N_NODES + 3) / 4;
        const int gemmGrid = (N_NODES + 127) / 128;
        k_spmv<128><<<spmvGrid, 256, 0, stream>>>(rp, cw, xb, bufB);
        k_spmv<128><<<spmvGrid, 256, 0, stream>>>(rp, cw, bufB, bufC);
        k_gemm3<128, 192, false><<<gemmGrid, 256, 0, stream>>>(xb, bufB, bufC, Wt1,
                                                               b1, bufA, batch, psum);
        k_spmv<192><<<spmvGrid, 256, 0, stream>>>(rp, cw, bufA, bufB);
        k_spmv<192><<<spmvGrid, 256, 0, stream>>>(rp, cw, bufB, bufC);
        k_gemm3<192, 192, false><<<gemmGrid, 256, 0, stream>>>(bufA, bufB, bufC, Wt2,
                                                               b2, bufD, batch, psum);
        k_spmv<192><<<spmvGrid, 256, 0, stream>>>(rp, cw, bufD, bufB);
        k_spmv<192><<<spmvGrid, 256, 0, stream>>>(rp, cw, bufB, bufC);
        k_gemm3<192, 128, true><<<gemmGrid, 256, 0, stream>>>(
            bufD, bufB, bufC, Wt3, b3, nullptr, batch, psum);
        k_head<<<N_GRAPHS, 64, 0, stream>>>(psum, batch, fcw, fcb, out);
    }
}

// Round 12
// 457.116 us; speedup vs baseline: 2.8210x; 2.8210x over previous
//
#include <hip/hip_runtime.h>
#include <math.h>

#define N_NODES 50000
#define N_EDGES 800000
#define N_GRAPHS 64
#define F_INN 128
#define F_HID 192
#define F_OUTT 128
#define N_CLS 10

typedef short short8 __attribute__((ext_vector_type(8)));
typedef float f32x4 __attribute__((ext_vector_type(4)));

static __device__ inline unsigned short f2bf(float f) {
    unsigned int u = __float_as_uint(f);
    unsigned int r = (u + 0x7FFFu + ((u >> 16) & 1u)) >> 16;  // RNE
    return (unsigned short)r;
}
static __device__ inline float bf2f(unsigned short h) {
    return __uint_as_float(((unsigned int)h) << 16);
}

// ---------------- CSR build ----------------
// k_deg records each edge's rank (atomic return is free); scatter is then
// atomic-free. 1 edge/thread (TLP > ILP for random atomics — round-6 lesson).
__global__ void k_deg(const int* __restrict__ row, int* __restrict__ cnt,
                      int* __restrict__ rank) {
    int e = blockIdx.x * 256 + threadIdx.x;
    if (e < N_EDGES) rank[e] = atomicAdd(&cnt[row[e]], 1);
}

__global__ void k_scan1(const int* __restrict__ cnt, int* __restrict__ rp,
                        int* __restrict__ part, float* __restrict__ dis) {
    __shared__ int s[256];
    int base = blockIdx.x * 512;
    int i0 = base + 2 * threadIdx.x;
    int v0 = (i0 < N_NODES) ? cnt[i0] : 0;
    int v1 = (i0 + 1 < N_NODES) ? cnt[i0 + 1] : 0;
    if (i0 < N_NODES) dis[i0] = v0 > 0 ? rsqrtf((float)v0) : 0.f;
    if (i0 + 1 < N_NODES) dis[i0 + 1] = v1 > 0 ? rsqrtf((float)v1) : 0.f;
    int tsum = v0 + v1;
    s[threadIdx.x] = tsum;
    __syncthreads();
    for (int off = 1; off < 256; off <<= 1) {
        int val = (threadIdx.x >= off) ? s[threadIdx.x - off] : 0;
        __syncthreads();
        s[threadIdx.x] += val;
        __syncthreads();
    }
    int excl = s[threadIdx.x] - tsum;
    if (i0 < N_NODES) rp[i0] = excl;
    if (i0 + 1 < N_NODES) rp[i0 + 1] = excl + v0;
    if (threadIdx.x == 255) part[blockIdx.x] = s[255];
}

// scan phases 2+3 fused: each block reduces part[0..b-1] itself (nb<=128).
__global__ void k_scan3(int* __restrict__ rp, const int* __restrict__ part,
                        int nb) {
    __shared__ int s[128];
    int t = threadIdx.x;
    int b = blockIdx.x;
    if (t < 128) s[t] = (t < b && t < nb) ? part[t] : 0;
    __syncthreads();
    for (int off = 64; off > 0; off >>= 1) {
        if (t < off) s[t] += s[t + off];
        __syncthreads();
    }
    int add = s[0];
    int i0 = b * 512 + 2 * t;
    if (i0 < N_NODES) rp[i0] += add;
    if (i0 + 1 < N_NODES) rp[i0 + 1] += add;
    if (b == 0 && t == 0) rp[N_NODES] = N_EDGES;
}

// packed CSR payload: (col, weight-bits). Atomic-free: pos = rp[r] + rank[e].
__global__ void k_scatter(const int* __restrict__ row, const int* __restrict__ col,
                          const float* __restrict__ dis, const int* __restrict__ rp,
                          const int* __restrict__ rank, int2* __restrict__ cw) {
    int e = blockIdx.x * 256 + threadIdx.x;
    if (e < N_EDGES) {
        int r = row[e], c = col[e];
        int pos = rp[r] + rank[e];
        int2 v;
        v.x = c;
        v.y = __float_as_int(-dis[r] * dis[c]);
        cw[pos] = v;
    }
}

// ---------------- fused fp32->bf16 conversions + workspace zeroing ---------
// Chebyshev weight folding: out = Tx0(W0-W2) + G1*W1 + G2*(2*W2), where
// G1 = L*Tx0, G2 = L*G1 — SpMV needs no alpha/beta epilogues.
// Tail of the index space zeroes cnt and psum (replaces hipMemsetAsync).
#define NX (N_NODES * F_INN)
#define NW1 (3 * 128 * 192)
#define NW2 (3 * 192 * 192)
#define NW3 (3 * 192 * 128)
#define NPS (N_GRAPHS * F_OUTT)
__global__ void k_convAll(const float* __restrict__ x, const float* __restrict__ W1,
                          const float* __restrict__ W2, const float* __restrict__ W3,
                          unsigned short* __restrict__ xb,
                          unsigned short* __restrict__ Wt1,
                          unsigned short* __restrict__ Wt2,
                          unsigned short* __restrict__ Wt3,
                          int* __restrict__ cnt, float* __restrict__ psum) {
    int idx = blockIdx.x * 256 + threadIdx.x;
    if (idx < NX) {
        xb[idx] = f2bf(x[idx]);
        return;
    }
    idx -= NX;
    if (idx < NW1) {  // W[j][k][n] -> Wt[j][n][k], Fin=128, Fout=192
        int per = 128 * 192;
        int j = idx / per, r = idx - j * per;
        int k = r / 192, n = r - k * 192;
        float v = (j == 0) ? (W1[idx] - W1[idx + 2 * per])
                           : (j == 2 ? 2.f * W1[idx] : W1[idx]);
        Wt1[j * per + n * 128 + k] = f2bf(v);
        return;
    }
    idx -= NW1;
    if (idx < NW2) {  // Fin=192, Fout=192
        int per = 192 * 192;
        int j = idx / per, r = idx - j * per;
        int k = r / 192, n = r - k * 192;
        float v = (j == 0) ? (W2[idx] - W2[idx + 2 * per])
                           : (j == 2 ? 2.f * W2[idx] : W2[idx]);
        Wt2[j * per + n * 192 + k] = f2bf(v);
        return;
    }
    idx -= NW2;
    if (idx < NW3) {  // Fin=192, Fout=128
        int per = 192 * 128;
        int j = idx / per, r = idx - j * per;
        int k = r / 128, n = r - k * 128;
        float v = (j == 0) ? (W3[idx] - W3[idx + 2 * per])
                           : (j == 2 ? 2.f * W3[idx] : W3[idx]);
        Wt3[j * per + n * 192 + k] = f2bf(v);
        return;
    }
    idx -= NW3;
    if (idx < N_NODES) {
        cnt[idx] = 0;
        return;
    }
    idx -= N_NODES;
    if (idx < NPS) psum[idx] = 0.f;
}

// ---------------- SpMV (bf16 in/out, fp32 accum): y = L_hat @ h -----------
// One wave per row; lane l owns feats {2l,2l+1} (uint gather) + 128+l for
// F=192. Wave-uniform edge metadata via readfirstlane; unroll x8.
// NOTE (round 8): structural floor — FETCH == h-size x 8 XCDs (compulsory
// replication) at the ~3.7 TB/s fabric ceiling. Round 11 proved fusing this
// into a high-LDS/VGPR coop kernel collapses its occupancy (61%->24%) and
// 2.5x's total time — keep it standalone.
template <int F>
__global__ void k_spmv(const int* __restrict__ rp, const int2* __restrict__ cw,
                       const unsigned short* __restrict__ h,
                       unsigned short* __restrict__ y) {
    constexpr bool EX = (F > 128);
    constexpr int FU = F / 2;  // uints per row
    int wave = threadIdx.x >> 6;
    int lane = threadIdx.x & 63;
    int r = blockIdx.x * 4 + wave;
    if (r >= N_NODES) return;
    int e0 = __builtin_amdgcn_readfirstlane(rp[r]);
    int e1 = __builtin_amdgcn_readfirstlane(rp[r + 1]);
    const unsigned int* hu = (const unsigned int*)h;
    float a0 = 0.f, a1 = 0.f, a2 = 0.f;
    int e = e0;
    for (; e + 8 <= e1; e += 8) {
        int colv[8];
        float wv[8];
#pragma unroll
        for (int u = 0; u < 8; u++) {
            int2 p = cw[e + u];
            colv[u] = __builtin_amdgcn_readfirstlane(p.x);
            wv[u] = __uint_as_float(__builtin_amdgcn_readfirstlane(p.y));
        }
        unsigned int g[8];
        unsigned short s[8];
#pragma unroll
        for (int u = 0; u < 8; u++) {
            g[u] = hu[colv[u] * FU + lane];
            if constexpr (EX) s[u] = h[colv[u] * F + 128 + lane];
        }
#pragma unroll
        for (int u = 0; u < 8; u++) {
            a0 += wv[u] * bf2f((unsigned short)g[u]);
            a1 += wv[u] * bf2f((unsigned short)(g[u] >> 16));
            if constexpr (EX) a2 += wv[u] * bf2f(s[u]);
        }
    }
    for (; e + 4 <= e1; e += 4) {
        int colv[4];
        float wv[4];
#pragma unroll
        for (int u = 0; u < 4; u++) {
            int2 p = cw[e + u];
            colv[u] = __builtin_amdgcn_readfirstlane(p.x);
            wv[u] = __uint_as_float(__builtin_amdgcn_readfirstlane(p.y));
        }
        unsigned int g[4];
        unsigned short s[4];
#pragma unroll
        for (int u = 0; u < 4; u++) {
            g[u] = hu[colv[u] * FU + lane];
            if constexpr (EX) s[u] = h[colv[u] * F + 128 + lane];
        }
#pragma unroll
        for (int u = 0; u < 4; u++) {
            a0 += wv[u] * bf2f((unsigned short)g[u]);
            a1 += wv[u] * bf2f((unsigned short)(g[u] >> 16));
            if constexpr (EX) a2 += wv[u] * bf2f(s[u]);
        }
    }
    for (; e < e1; e++) {
        int2 p = cw[e];
        int c = __builtin_amdgcn_readfirstlane(p.x);
        float w = __uint_as_float(__builtin_amdgcn_readfirstlane(p.y));
        unsigned int g = hu[c * FU + lane];
        a0 += w * bf2f((unsigned short)g);
        a1 += w * bf2f((unsigned short)(g >> 16));
        if constexpr (EX) a2 += w * bf2f(h[c * F + 128 + lane]);
    }
    ((unsigned int*)y)[r * FU + lane] =
        (unsigned int)f2bf(a0) | ((unsigned int)f2bf(a1) << 16);
    if constexpr (EX) y[r * F + 128 + lane] = f2bf(a2);
}

// ---------------- fused 3-matrix bf16 MFMA GEMM ----------------
// C = A0@W'[0]+A1@W'[1]+A2@W'[2]+bias. One block owns the FULL Fout width
// (N-tiled grids re-read A across XCDs — compulsory fabric fills).
// Block: 256 thr = 4 waves; tile M=128 x N=Fout; wave = 32 rows.
// FUSE_POOL: skip the C write; pool the fp32 tile into psum instead
// (layer-3 output is consumed only by global mean pool). Fast path when a
// wave's 32 rows share one graph: in-lane row-sum + shfl_xor quad-reduce
// -> 8 atomics per wave; boundary waves take per-row atomics.
template <int Fin, int Fout, bool FUSE_POOL>
__global__ __launch_bounds__(256) void k_gemm3(
    const unsigned short* __restrict__ A0, const unsigned short* __restrict__ A1,
    const unsigned short* __restrict__ A2, const unsigned short* __restrict__ Wt,
    const float* __restrict__ bias, unsigned short* __restrict__ C,
    const int* __restrict__ batch, float* __restrict__ psum) {
    constexpr int NF = Fout / 16;  // N-fragments per wave row
    constexpr int BP = Fout / 64;  // B staging passes
    __shared__ unsigned short As[128 * 40];
    __shared__ unsigned short Bs[Fout * 40];
    int t = threadIdx.x;
    int w = t >> 6;
    int lane = t & 63;
    int ml = lane & 15;
    int quad = lane >> 4;
    int mBase = blockIdx.x * 128;
    constexpr int per = Fin * Fout;

    f32x4 acc[2][NF];
#pragma unroll
    for (int i = 0; i < 2; i++)
#pragma unroll
        for (int jn = 0; jn < NF; jn++) acc[i][jn] = (f32x4){0.f, 0.f, 0.f, 0.f};

    int srow = t >> 2;   // 0..63
    int schunk = t & 3;  // 16B chunk within 32-k slab
    constexpr int nChunks = (3 * Fin) >> 5;

    for (int ch = 0; ch < nChunks; ch++) {
        int kg = ch << 5;
        int j = kg / Fin;
        int kk = kg - j * Fin;
        const unsigned short* Aj = (j == 0) ? A0 : (j == 1) ? A1 : A2;
        if (ch > 0) __syncthreads();
#pragma unroll
        for (int pass = 0; pass < 2; pass++) {
            int row = srow + pass * 64;
            int gm = mBase + row;
            uint4 v = {0u, 0u, 0u, 0u};
            if (gm < N_NODES)
                v = *(const uint4*)(Aj + (size_t)gm * Fin + kk + schunk * 8);
            *(uint4*)&As[row * 40 + schunk * 8] = v;
        }
#pragma unroll
        for (int pass = 0; pass < BP; pass++) {
            int row = srow + pass * 64;  // n index 0..Fout-1
            const unsigned short* src =
                Wt + (size_t)j * per + (size_t)row * Fin + kk + schunk * 8;
            *(uint4*)&Bs[row * 40 + schunk * 8] = *(const uint4*)src;
        }
        __syncthreads();

        short8 afr[2];
#pragma unroll
        for (int i = 0; i < 2; i++)
            afr[i] = *(const short8*)&As[(w * 32 + i * 16 + ml) * 40 + quad * 8];
#pragma unroll
        for (int jn = 0; jn < NF; jn++) {
            short8 bfr = *(const short8*)&Bs[(jn * 16 + ml) * 40 + quad * 8];
#pragma unroll
            for (int i = 0; i < 2; i++)
                acc[i][jn] = __builtin_amdgcn_mfma_f32_16x16x32_bf16(
                    afr[i], bfr, acc[i][jn], 0, 0, 0);
        }
    }

    float biasv[NF];
#pragma unroll
    for (int jn = 0; jn < NF; jn++) biasv[jn] = bias[jn * 16 + ml];

    if constexpr (!FUSE_POOL) {
#pragma unroll
        for (int i = 0; i < 2; i++) {
#pragma unroll
            for (int r = 0; r < 4; r++) {
                int m = mBase + w * 32 + i * 16 + quad * 4 + r;
                if (m < N_NODES) {
                    unsigned short* cp = C + (size_t)m * Fout + ml;
#pragma unroll
                    for (int jn = 0; jn < NF; jn++)
                        cp[jn * 16] = f2bf(acc[i][jn][r] + biasv[jn]);
                }
            }
        }
    } else {
        int m0 = mBase + w * 32;
        if (m0 >= N_NODES) return;
        int mlast = m0 + 31;
        if (mlast >= N_NODES) mlast = N_NODES - 1;
        int g0 = batch[m0];
        int g1 = batch[mlast];
        if (g0 == g1) {
            // fast path: whole wave in one graph
#pragma unroll
            for (int jn = 0; jn < NF; jn++) {
                float pv = 0.f;
#pragma unroll
                for (int i = 0; i < 2; i++)
#pragma unroll
                    for (int r = 0; r < 4; r++) {
                        int m = m0 + i * 16 + quad * 4 + r;
                        if (m < N_NODES) pv += acc[i][jn][r] + biasv[jn];
                    }
                pv += __shfl_xor(pv, 16);
                pv += __shfl_xor(pv, 32);
                if (lane < 16) atomicAdd(&psum[g0 * F_OUTT + ml + jn * 16], pv);
            }
        } else {
            // boundary wave: per-row atomics
#pragma unroll
            for (int i = 0; i < 2; i++)
#pragma unroll
                for (int r = 0; r < 4; r++) {
                    int m = m0 + i * 16 + quad * 4 + r;
                    if (m < N_NODES) {
                        int g = batch[m];
#pragma unroll
                        for (int jn = 0; jn < NF; jn++)
                            atomicAdd(&psum[g * F_OUTT + ml + jn * 16],
                                      acc[i][jn][r] + biasv[jn]);
                    }
                }
        }
    }
}

// ---------------- head: mean + fc + log_softmax ----------------
__global__ void k_head(const float* __restrict__ psum, const int* __restrict__ batch,
                       const float* __restrict__ fcw, const float* __restrict__ fcb,
                       float* __restrict__ out) {
    int g = blockIdx.x;
    int c = threadIdx.x;  // 64 threads, lanes >= N_CLS idle
    __shared__ float sl[N_CLS];
    int a = 0, b = N_NODES;
    while (a < b) { int m = (a + b) >> 1; if (batch[m] < g) a = m + 1; else b = m; }
    int lo = a;
    a = lo; b = N_NODES;
    while (a < b) { int m = (a + b) >> 1; if (batch[m] < g + 1) a = m + 1; else b = m; }
    float inv = 1.f / fmaxf((float)(a - lo), 1.f);
    float l = 0.f;
    if (c < N_CLS) {
        l = fcb[c];
        for (int k = 0; k < F_OUTT; k++)
            l += psum[g * F_OUTT + k] * inv * fcw[k * N_CLS + c];
        sl[c] = l;
    }
    __syncthreads();
    if (c < N_CLS) {
        float m = -1e30f;
        for (int i = 0; i < N_CLS; i++) m = fmaxf(m, sl[i]);
        float s = 0.f;
        for (int i = 0; i < N_CLS; i++) s += expf(sl[i] - m);
        out[g * N_CLS + c] = l - m - logf(s);
    }
}

extern "C" void kernel_launch(void* const* d_in, const int* in_sizes, int n_in,
                              void* d_out, int out_size, void* d_ws, size_t ws_size,
                              hipStream_t stream) {
    const float* x = (const float*)d_in[0];
    const int* ei = (const int*)d_in[1];
    const int* batch = (const int*)d_in[2];
    const float* W1 = (const float*)d_in[3];
    const float* b1 = (const float*)d_in[4];
    const float* W2 = (const float*)d_in[5];
    const float* b2 = (const float*)d_in[6];
    const float* W3 = (const float*)d_in[7];
    const float* b3 = (const float*)d_in[8];
    const float* fcw = (const float*)d_in[9];
    const float* fcb = (const float*)d_in[10];
    float* out = (float*)d_out;
    const int* row = ei;
    const int* col = ei + N_EDGES;

    char* p = (char*)d_ws;
    auto carve = [&](size_t bytes) {
        char* q = p;
        p += (bytes + 255) & ~(size_t)255;
        return q;
    };
    int* cnt = (int*)carve(N_NODES * 4);
    int* rank = (int*)carve((size_t)N_EDGES * 4);
    float* dis = (float*)carve(N_NODES * 4);
    int* rp = (int*)carve((N_NODES + 1) * 4);
    int* part = (int*)carve(128 * 4);
    int2* cw = (int2*)carve((size_t)N_EDGES * 8);
    unsigned short* xb = (unsigned short*)carve((size_t)N_NODES * F_INN * 2);
    size_t hbytes = (size_t)N_NODES * 192 * 2;
    unsigned short* bufA = (unsigned short*)carve(hbytes);
    unsigned short* bufB = (unsigned short*)carve(hbytes);
    unsigned short* bufC = (unsigned short*)carve(hbytes);
    unsigned short* bufD = (unsigned short*)carve(hbytes);
    unsigned short* Wt1 = (unsigned short*)carve(NW1 * 2);
    unsigned short* Wt2 = (unsigned short*)carve(NW2 * 2);
    unsigned short* Wt3 = (unsigned short*)carve(NW3 * 2);
    float* psum = (float*)carve(NPS * 4);

    // conv + zeroing first (replaces all memsets; stream order covers deps)
    {
        int tot = NX + NW1 + NW2 + NW3 + N_NODES + NPS;
        k_convAll<<<(tot + 255) / 256, 256, 0, stream>>>(x, W1, W2, W3, xb, Wt1, Wt2,
                                                         Wt3, cnt, psum);
    }

    k_deg<<<(N_EDGES + 255) / 256, 256, 0, stream>>>(row, cnt, rank);
    int nb = (N_NODES + 511) / 512;  // 98
    k_scan1<<<nb, 256, 0, stream>>>(cnt, rp, part, dis);
    k_scan3<<<nb, 256, 0, stream>>>(rp, part, nb);
    k_scatter<<<(N_EDGES + 255) / 256, 256, 0, stream>>>(row, col, dis, rp, rank, cw);

    const int spmvGrid = (N_NODES + 3) / 4;
    const int gemmGrid = (N_NODES + 127) / 128;

    // Layer 1: G1 = L x, G2 = L G1; out = x(W0-W2) + G1 W1 + G2 (2W2) + b
    k_spmv<128><<<spmvGrid, 256, 0, stream>>>(rp, cw, xb, bufB);
    k_spmv<128><<<spmvGrid, 256, 0, stream>>>(rp, cw, bufB, bufC);
    k_gemm3<128, 192, false><<<gemmGrid, 256, 0, stream>>>(xb, bufB, bufC, Wt1, b1,
                                                           bufA, batch, psum);
    // Layer 2
    k_spmv<192><<<spmvGrid, 256, 0, stream>>>(rp, cw, bufA, bufB);
    k_spmv<192><<<spmvGrid, 256, 0, stream>>>(rp, cw, bufB, bufC);
    k_gemm3<192, 192, false><<<gemmGrid, 256, 0, stream>>>(bufA, bufB, bufC, Wt2, b2,
                                                           bufD, batch, psum);
    // Layer 3: pool fused into epilogue; no C write
    k_spmv<192><<<spmvGrid, 256, 0, stream>>>(rp, cw, bufD, bufB);
    k_spmv<192><<<spmvGrid, 256, 0, stream>>>(rp, cw, bufB, bufC);
    k_gemm3<192, 128, true><<<gemmGrid, 256, 0, stream>>>(bufD, bufB, bufC, Wt3, b3,
                                                          nullptr, batch, psum);

    k_head<<<N_GRAPHS, 64, 0, stream>>>(psum, batch, fcw, fcb, out);
}